// Round 4
// baseline (360.449 us; speedup 1.0000x reference)
//
#include <hip/hip_runtime.h>
#include <hip/hip_bf16.h>

typedef __attribute__((ext_vector_type(8))) short short8;
typedef __attribute__((ext_vector_type(4))) float f32x4;

constexpr int B_ = 4, S_ = 2048, D_ = 512, H_ = 8, DP_ = 64;
constexpr int M_ = B_ * S_;  // 8192 rows

__device__ __forceinline__ unsigned short f2b(float f) {
    __hip_bfloat16 h = __float2bfloat16(f);
    return *reinterpret_cast<unsigned short*>(&h);
}

__device__ __forceinline__ void gload_lds16(const unsigned short* g, unsigned short* l) {
    __builtin_amdgcn_global_load_lds((const __attribute__((address_space(1))) void*)g,
                                     (__attribute__((address_space(3))) void*)l, 16, 0, 0);
}

#define MFMA16(a, b, c) __builtin_amdgcn_mfma_f32_16x16x32_bf16((a), (b), (c), 0, 0, 0)

// ---------------- fp32 -> bf16 convert (x) ----------------
__global__ __launch_bounds__(256)
void convert_x(const float* __restrict__ in, unsigned short* __restrict__ out) {
    int i = blockIdx.x * 256 + threadIdx.x;   // one float4 per thread
    float4 v = ((const float4*)in)[i];
    ushort4 o;
    o.x = f2b(v.x); o.y = f2b(v.y); o.z = f2b(v.z); o.w = f2b(v.w);
    ((ushort4*)out)[i] = o;
}

// ---------------- weight transpose + convert: Wt[n][k] = bf16(W[k][n]) ----------------
__global__ __launch_bounds__(256)
void transpose_w(const float* __restrict__ w0, const float* __restrict__ w1,
                 const float* __restrict__ w2, const float* __restrict__ w3,
                 unsigned short* __restrict__ outw) {
    const float* in = (blockIdx.z == 0) ? w0 : (blockIdx.z == 1) ? w1
                     : (blockIdx.z == 2) ? w2 : w3;
    unsigned short* out = outw + (size_t)blockIdx.z * D_ * D_;
    __shared__ float t[64][65];
    int k0 = blockIdx.x * 64, n0 = blockIdx.y * 64;
    int tx = threadIdx.x & 63, ty = threadIdx.x >> 6;
#pragma unroll
    for (int i = 0; i < 16; i++) {
        int r = ty * 16 + i;
        t[r][tx] = in[(size_t)(k0 + r) * D_ + n0 + tx];
    }
    __syncthreads();
#pragma unroll
    for (int i = 0; i < 16; i++) {
        int r = ty * 16 + i;
        out[(size_t)(n0 + r) * D_ + k0 + tx] = f2b(t[tx][r]);
    }
}

// ---------------- QKV GEMM (Q,K only): [8192x512] @ W -> scatter to [B][H][S][64] ----------------
__global__ __launch_bounds__(256, 2)
void gemm_qkv(const unsigned short* __restrict__ X,
              const unsigned short* __restrict__ Wt,   // [2][512][512] transposed bf16
              unsigned short* __restrict__ QKV) {      // [2][B][H][S][64]
    const unsigned short* Bt = Wt + (size_t)blockIdx.z * D_ * D_;
    unsigned short* out = QKV + (size_t)blockIdx.z * M_ * D_;
    int m0 = blockIdx.x * 128, n0 = blockIdx.y * 128;
    int tid = threadIdx.x;
    int wave = tid >> 6, lane = tid & 63, l16 = lane & 15, quad = lane >> 4;
    int wm = (wave >> 1) * 64, wn = (wave & 1) * 64;

    __shared__ __align__(16) unsigned short As[128][40];
    __shared__ __align__(16) unsigned short Bs[128][40];

    f32x4 acc[4][4];
    const f32x4 zf = {0.f, 0.f, 0.f, 0.f};
#pragma unroll
    for (int i = 0; i < 4; i++)
#pragma unroll
        for (int j = 0; j < 4; j++) acc[i][j] = zf;

    for (int k0 = 0; k0 < D_; k0 += 32) {
        __syncthreads();
#pragma unroll
        for (int i = 0; i < 2; i++) {
            int c = tid + i * 256;
            int row = c >> 2, off = (c & 3) * 8;
            *(short8*)&As[row][off] = *(const short8*)(X + (size_t)(m0 + row) * D_ + k0 + off);
            *(short8*)&Bs[row][off] = *(const short8*)(Bt + (size_t)(n0 + row) * D_ + k0 + off);
        }
        __syncthreads();
        short8 af[4], bf[4];
#pragma unroll
        for (int mt = 0; mt < 4; mt++) af[mt] = *(const short8*)&As[wm + mt * 16 + l16][quad * 8];
#pragma unroll
        for (int nt = 0; nt < 4; nt++) bf[nt] = *(const short8*)&Bs[wn + nt * 16 + l16][quad * 8];
#pragma unroll
        for (int mt = 0; mt < 4; mt++)
#pragma unroll
            for (int nt = 0; nt < 4; nt++)
                acc[mt][nt] = MFMA16(af[mt], bf[nt], acc[mt][nt]);
    }
    // epilogue: C/D layout col=lane&15, row=quad*4+r; scatter to [B][H][S][64]
#pragma unroll
    for (int mt = 0; mt < 4; mt++)
#pragma unroll
        for (int nt = 0; nt < 4; nt++)
#pragma unroll
            for (int r = 0; r < 4; r++) {
                int m = m0 + wm + mt * 16 + quad * 4 + r;
                int n = n0 + wn + nt * 16 + l16;
                int bb = m >> 11, ss = m & 2047, hh = n >> 6, dd = n & 63;
                out[(((size_t)bb * H_ + hh) * S_ + ss) * DP_ + dd] = f2b(acc[mt][nt][r]);
            }
}

// ---------------- V^T GEMM: Vt_b = Wv^T (.) X_b^T  -> [B][512][2048] ----------------
// out[m][n] = sum_k Wv^T[m][k] * X[b*S+n][k] = V_b[n][m]  (coalesced along n=s)
__global__ __launch_bounds__(256, 2)
void gemm_vt(const unsigned short* __restrict__ X,
             const unsigned short* __restrict__ Wt,   // Wv^T [512][512] bf16
             unsigned short* __restrict__ Vt) {       // [B][D][S] bf16
    int bb = blockIdx.z;
    int m0 = blockIdx.x * 128, n0 = blockIdx.y * 128;
    int tid = threadIdx.x;
    int wave = tid >> 6, lane = tid & 63, l16 = lane & 15, quad = lane >> 4;
    int wm = (wave >> 1) * 64, wn = (wave & 1) * 64;

    __shared__ __align__(16) unsigned short As[128][40];
    __shared__ __align__(16) unsigned short Bs[128][40];

    f32x4 acc[4][4];
    const f32x4 zf = {0.f, 0.f, 0.f, 0.f};
#pragma unroll
    for (int i = 0; i < 4; i++)
#pragma unroll
        for (int j = 0; j < 4; j++) acc[i][j] = zf;

    for (int k0 = 0; k0 < D_; k0 += 32) {
        __syncthreads();
#pragma unroll
        for (int i = 0; i < 2; i++) {
            int c = tid + i * 256;
            int row = c >> 2, off = (c & 3) * 8;
            *(short8*)&As[row][off] = *(const short8*)(Wt + (size_t)(m0 + row) * D_ + k0 + off);
            *(short8*)&Bs[row][off] = *(const short8*)(X + (size_t)(bb * S_ + n0 + row) * D_ + k0 + off);
        }
        __syncthreads();
        short8 af[4], bf[4];
#pragma unroll
        for (int mt = 0; mt < 4; mt++) af[mt] = *(const short8*)&As[wm + mt * 16 + l16][quad * 8];
#pragma unroll
        for (int nt = 0; nt < 4; nt++) bf[nt] = *(const short8*)&Bs[wn + nt * 16 + l16][quad * 8];
#pragma unroll
        for (int mt = 0; mt < 4; mt++)
#pragma unroll
            for (int nt = 0; nt < 4; nt++)
                acc[mt][nt] = MFMA16(af[mt], bf[nt], acc[mt][nt]);
    }
#pragma unroll
    for (int mt = 0; mt < 4; mt++)
#pragma unroll
        for (int nt = 0; nt < 4; nt++)
#pragma unroll
            for (int r = 0; r < 4; r++) {
                int m = m0 + wm + mt * 16 + quad * 4 + r;   // d-row in [0,512)
                int n = n0 + wn + nt * 16 + l16;            // s in [0,2048)
                Vt[((size_t)bb * D_ + m) * S_ + n] = f2b(acc[mt][nt][r]);
            }
}

// ---------------- flash attention: per (b,h,64-q-rows) block, software-pipelined ----------------
// Swapped QK^T; K tile fully prefetched into registers (reloaded during PV); V tile
// staged via global_load_lds with XOR-swizzle (linear LDS dest + inverse-swizzled global
// source + swizzled read); defer-max softmax. No loads on the QK critical path.
__global__ __launch_bounds__(256, 4)
void flash_attn(const unsigned short* __restrict__ Qg, const unsigned short* __restrict__ Kg,
                const unsigned short* __restrict__ Vt, unsigned short* __restrict__ ctx) {
    int bid0 = blockIdx.x;
    int bid = (bid0 & 7) * 128 + (bid0 >> 3);   // XCD swizzle: 4 heads per XCD (1024 = 8*128)
    int qt = bid & 31, hh = (bid >> 5) & 7, bb = bid >> 8;
    int tid = threadIdx.x;
    int wave = tid >> 6, lane = tid & 63, l16 = lane & 15, quad = lane >> 4;
    int qh = quad >> 1, ql = quad & 1;

    size_t bh = ((size_t)bb * H_ + hh) * S_ * DP_;
    const unsigned short* Qb = Qg + bh;
    const unsigned short* Kb = Kg + bh;
    const unsigned short* Vb = Vt + bh;   // V^T head slice: 64 rows (d), 2048 cols (s)

    // V^T tile [64 d][128 s] bf16, UNPADDED, chunk-XOR swizzled: 16B chunk at
    // physical index p holds logical chunk p ^ (row&7). Written linearly by
    // global_load_lds from an inverse-swizzled global address (m201/m231 pattern).
    __shared__ __align__(16) unsigned short Vts[64][128];
    // per-wave P tile [16 q][128 k], chunk-XOR swizzle (proven R3)
    __shared__ __align__(16) unsigned short Ps[4][16][128];

    const int psw = l16 & 7;
    const int vrow = 4 * wave + (lane >> 4);   // V-staging row (+16*i)

    // Q fragments in registers for the whole kernel
    short8 qf0, qf1;
    {
        const unsigned short* qp = Qb + (size_t)(qt * 64 + wave * 16 + l16) * DP_ + quad * 8;
        qf0 = *(const short8*)qp;
        qf1 = *(const short8*)(qp + 32);
    }

    // prologue: issue V tile 0 DMA + load K tile 0 into registers
#pragma unroll
    for (int i = 0; i < 4; i++) {
        int row = vrow + 16 * i;
        int lc = (lane & 15) ^ (row & 7);
        gload_lds16(Vb + (size_t)row * S_ + lc * 8, &Vts[16 * i + 4 * wave][0]);
    }
    short8 kf0[8], kf1[8];
#pragma unroll
    for (int nt = 0; nt < 8; nt++) {
        const unsigned short* kp = Kb + (size_t)(nt * 16 + l16) * DP_ + quad * 8;
        kf0[nt] = *(const short8*)kp;
        kf1[nt] = *(const short8*)(kp + 32);
    }

    const f32x4 zf = {0.f, 0.f, 0.f, 0.f};
    f32x4 oacc[4];
#pragma unroll
    for (int i = 0; i < 4; i++) oacc[i] = zf;
    float m2 = -1e30f;   // running max offset in log2 domain (possibly stale: defer-max)
    float lrow = 0.f;
    constexpr float c1 = 0.125f * 1.44269504088896f;  // (1/sqrt(64)) * log2(e)

    for (int kv = 0; kv < S_; kv += 128) {
        int kvn = kv + 128;

        // (1) S^T = K Q^T entirely from registers: sacc[nt][r] = S[q=l16][k=16nt+4quad+r]
        __builtin_amdgcn_s_setprio(1);
        f32x4 sacc[8];
#pragma unroll
        for (int nt = 0; nt < 8; nt++) {
            f32x4 s = zf;
            s = MFMA16(kf0[nt], qf0, s);
            s = MFMA16(kf1[nt], qf1, s);
            sacc[nt] = s;
        }
        __builtin_amdgcn_s_setprio(0);

        // (2) defer-max online softmax (lane-local row q = l16), Ps writes (per-wave)
        float t8[8];
#pragma unroll
        for (int nt = 0; nt < 8; nt++)
            t8[nt] = fmaxf(fmaxf(sacc[nt][0], sacc[nt][1]), fmaxf(sacc[nt][2], sacc[nt][3]));
        float g = fmaxf(fmaxf(fmaxf(t8[0], t8[1]), fmaxf(t8[2], t8[3])),
                        fmaxf(fmaxf(t8[4], t8[5]), fmaxf(t8[6], t8[7])));
        g = fmaxf(g, __shfl_xor(g, 16));
        g = fmaxf(g, __shfl_xor(g, 32));
        g *= c1;
        float alpha = 1.0f;
        bool need = !__all(g <= m2 + 8.0f);
        if (need) {
            float m2n = fmaxf(m2, g);
            alpha = __builtin_amdgcn_exp2f(m2 - m2n);
            m2 = m2n;
        }
        float rs = 0.f;
#pragma unroll
        for (int nt = 0; nt < 8; nt++) {
            float p0 = __builtin_amdgcn_exp2f(__builtin_fmaf(sacc[nt][0], c1, -m2));
            float p1 = __builtin_amdgcn_exp2f(__builtin_fmaf(sacc[nt][1], c1, -m2));
            float p2 = __builtin_amdgcn_exp2f(__builtin_fmaf(sacc[nt][2], c1, -m2));
            float p3 = __builtin_amdgcn_exp2f(__builtin_fmaf(sacc[nt][3], c1, -m2));
            rs += (p0 + p1) + (p2 + p3);
            ushort4 pk;
            pk.x = f2b(p0); pk.y = f2b(p1); pk.z = f2b(p2); pk.w = f2b(p3);
            int c8 = (2 * nt + qh) ^ psw;
            *(ushort4*)&Ps[wave][l16][c8 * 8 + 4 * ql] = pk;
        }
        rs += __shfl_xor(rs, 16);
        rs += __shfl_xor(rs, 32);
        lrow = alpha * lrow + rs;
        if (need) {
            float al0 = __shfl(alpha, quad * 4 + 0);
            float al1 = __shfl(alpha, quad * 4 + 1);
            float al2 = __shfl(alpha, quad * 4 + 2);
            float al3 = __shfl(alpha, quad * 4 + 3);
#pragma unroll
            for (int ot = 0; ot < 4; ot++) {
                oacc[ot][0] *= al0; oacc[ot][1] *= al1;
                oacc[ot][2] *= al2; oacc[ot][3] *= al3;
            }
        }

        // (3) barrier: V DMA (issued last iter) drained by the implicit vmcnt(0);
        //     also orders all waves past the previous PV reads.
        __syncthreads();

        // (4) K prefetch for next iter (lands under PV + next barrier), then PV
        if (kvn < S_) {
#pragma unroll
            for (int nt = 0; nt < 8; nt++) {
                const unsigned short* kp = Kb + (size_t)(kvn + nt * 16 + l16) * DP_ + quad * 8;
                kf0[nt] = *(const short8*)kp;
                kf1[nt] = *(const short8*)(kp + 32);
            }
        }
        __builtin_amdgcn_s_setprio(1);
#pragma unroll
        for (int kt = 0; kt < 4; kt++) {
            int pc = ((4 * kt + quad) ^ psw) * 8;   // same swizzled chunk for Ps AND Vts
            short8 pf = *(const short8*)&Ps[wave][l16][pc];
#pragma unroll
            for (int ot = 0; ot < 4; ot++) {
                short8 vf = *(const short8*)&Vts[ot * 16 + l16][pc];
                oacc[ot] = MFMA16(pf, vf, oacc[ot]);
            }
        }
        __builtin_amdgcn_s_setprio(0);

        // (5) all waves done reading Vts tile
        __syncthreads();

        // (6) issue next V tile DMA (in flight across next QK + softmax)
        if (kvn < S_) {
#pragma unroll
            for (int i = 0; i < 4; i++) {
                int row = vrow + 16 * i;
                int lc = (lane & 15) ^ (row & 7);
                gload_lds16(Vb + (size_t)row * S_ + kvn + lc * 8, &Vts[16 * i + 4 * wave][0]);
            }
        }
    }
    // epilogue: normalize (l for row q=quad*4+r via shfl), merge heads into [B][S][512]
    float lb0 = __shfl(lrow, quad * 4 + 0);
    float lb1 = __shfl(lrow, quad * 4 + 1);
    float lb2 = __shfl(lrow, quad * 4 + 2);
    float lb3 = __shfl(lrow, quad * 4 + 3);
    float iv0 = __builtin_amdgcn_rcpf(lb0);
    float iv1 = __builtin_amdgcn_rcpf(lb1);
    float iv2 = __builtin_amdgcn_rcpf(lb2);
    float iv3 = __builtin_amdgcn_rcpf(lb3);
#pragma unroll
    for (int ot = 0; ot < 4; ot++) {
        int srow0 = qt * 64 + wave * 16 + quad * 4;
        size_t base = ((size_t)bb * S_ + srow0) * D_ + hh * DP_ + ot * 16 + l16;
        ctx[base]          = f2b(oacc[ot][0] * iv0);
        ctx[base + D_]     = f2b(oacc[ot][1] * iv1);
        ctx[base + 2 * D_] = f2b(oacc[ot][2] * iv2);
        ctx[base + 3 * D_] = f2b(oacc[ot][3] * iv3);
    }
}

// ---------------- output projection GEMM -> fp32 scratch ----------------
__global__ __launch_bounds__(256, 2)
void gemm_proj(const unsigned short* __restrict__ A,   // ctx [8192][512] bf16
               const unsigned short* __restrict__ Bt,  // Wo^T [512][512] bf16
               float* __restrict__ outf) {             // [8192][512] fp32
    int m0 = blockIdx.x * 128, n0 = blockIdx.y * 128;
    int tid = threadIdx.x;
    int wave = tid >> 6, lane = tid & 63, l16 = lane & 15, quad = lane >> 4;
    int wm = (wave >> 1) * 64, wn = (wave & 1) * 64;

    __shared__ __align__(16) unsigned short As[128][40];
    __shared__ __align__(16) unsigned short Bs[128][40];

    f32x4 acc[4][4];
    const f32x4 zf = {0.f, 0.f, 0.f, 0.f};
#pragma unroll
    for (int i = 0; i < 4; i++)
#pragma unroll
        for (int j = 0; j < 4; j++) acc[i][j] = zf;

    for (int k0 = 0; k0 < D_; k0 += 32) {
        __syncthreads();
#pragma unroll
        for (int i = 0; i < 2; i++) {
            int c = tid + i * 256;
            int row = c >> 2, off = (c & 3) * 8;
            *(short8*)&As[row][off] = *(const short8*)(A + (size_t)(m0 + row) * D_ + k0 + off);
            *(short8*)&Bs[row][off] = *(const short8*)(Bt + (size_t)(n0 + row) * D_ + k0 + off);
        }
        __syncthreads();
        short8 af[4], bf[4];
#pragma unroll
        for (int mt = 0; mt < 4; mt++) af[mt] = *(const short8*)&As[wm + mt * 16 + l16][quad * 8];
#pragma unroll
        for (int nt = 0; nt < 4; nt++) bf[nt] = *(const short8*)&Bs[wn + nt * 16 + l16][quad * 8];
#pragma unroll
        for (int mt = 0; mt < 4; mt++)
#pragma unroll
            for (int nt = 0; nt < 4; nt++)
                acc[mt][nt] = MFMA16(af[mt], bf[nt], acc[mt][nt]);
    }
#pragma unroll
    for (int mt = 0; mt < 4; mt++)
#pragma unroll
        for (int nt = 0; nt < 4; nt++)
#pragma unroll
            for (int r = 0; r < 4; r++) {
                int m = m0 + wm + mt * 16 + quad * 4 + r;
                int n = n0 + wn + nt * 16 + l16;
                outf[(size_t)m * D_ + n] = acc[mt][nt][r];
            }
}

// ---------------- bias + residual + LayerNorm (all fp32), one block per row ----------------
__global__ __launch_bounds__(256, 4)
void ln_out(const float* __restrict__ tmp, const float* __restrict__ Xg,
            const float* __restrict__ bo, const float* __restrict__ gamma,
            const float* __restrict__ beta, float* __restrict__ outp) {
    int row = blockIdx.x;
    int tid = threadIdx.x;
    int lane = tid & 63, wave = tid >> 6;
    float resid[2];
#pragma unroll
    for (int i = 0; i < 2; i++) {
        int c = tid + i * 256;
        resid[i] = Xg[(size_t)row * D_ + c] + tmp[(size_t)row * D_ + c] + bo[c];
    }
    float sum = resid[0] + resid[1];
    float sq = resid[0] * resid[0] + resid[1] * resid[1];
#pragma unroll
    for (int off = 1; off < 64; off <<= 1) {
        sum += __shfl_xor(sum, off);
        sq += __shfl_xor(sq, off);
    }
    __shared__ float red[8];
    if (lane == 0) { red[wave] = sum; red[4 + wave] = sq; }
    __syncthreads();
    sum = red[0] + red[1] + red[2] + red[3];
    sq = red[4] + red[5] + red[6] + red[7];
    float mu = sum * (1.0f / D_);
    float var = sq * (1.0f / D_) - mu * mu;
    float rstd = rsqrtf(var + 1e-6f);
#pragma unroll
    for (int i = 0; i < 2; i++) {
        int c = tid + i * 256;
        float o = (resid[i] - mu) * rstd * gamma[c] + beta[c];
        outp[(size_t)row * D_ + c] = o;
    }
}

extern "C" void kernel_launch(void* const* d_in, const int* in_sizes, int n_in,
                              void* d_out, int out_size, void* d_ws, size_t ws_size,
                              hipStream_t stream) {
    const float* x     = (const float*)d_in[0];
    const float* wq    = (const float*)d_in[1];
    const float* wk    = (const float*)d_in[2];
    const float* wv    = (const float*)d_in[3];
    const float* wo    = (const float*)d_in[4];
    const float* bo    = (const float*)d_in[5];
    const float* gamma = (const float*)d_in[6];
    const float* beta  = (const float*)d_in[7];
    float* out = (float*)d_out;

    // ws layout (bf16 elems unless noted), total 34 MB:
    //   [xb 8MB | wt 2MB | Q,K,Vt 24MB]
    //   ctx aliases xb (xb dead after the projection GEMMs). fp32 tmp aliases Q (dead after flash).
    unsigned short* xb  = (unsigned short*)d_ws;                    // 8192*512 bf16
    unsigned short* wt  = xb + (size_t)M_ * D_;                     // 4*512*512 bf16
    unsigned short* Q   = wt + 4 * D_ * D_;
    unsigned short* K   = Q + (size_t)M_ * D_;
    unsigned short* Vt  = K + (size_t)M_ * D_;                      // [B][512][2048]
    unsigned short* ctx = xb;                                       // alias: xb dead
    float* tmp = (float*)Q;                                         // alias: Q/K/Vt dead

    convert_x<<<dim3(M_ * D_ / 4 / 256), 256, 0, stream>>>(x, xb);
    transpose_w<<<dim3(8, 8, 4), 256, 0, stream>>>(wq, wk, wv, wo, wt);
    gemm_qkv<<<dim3(64, 4, 2), 256, 0, stream>>>(xb, wt, Q);
    gemm_vt<<<dim3(4, 16, 4), 256, 0, stream>>>(xb, wt + 2 * (size_t)D_ * D_, Vt);
    flash_attn<<<dim3(1024), 256, 0, stream>>>(Q, K, Vt, ctx);
    gemm_proj<<<dim3(64, 4), 256, 0, stream>>>(ctx, wt + 3 * (size_t)D_ * D_, tmp);
    ln_out<<<dim3(8192), 256, 0, stream>>>(tmp, x, bo, gamma, beta, out);
}

// Round 5
// 274.414 us; speedup vs baseline: 1.3135x; 1.3135x over previous
//
#include <hip/hip_runtime.h>
#include <hip/hip_bf16.h>

typedef __attribute__((ext_vector_type(8))) short short8;
typedef __attribute__((ext_vector_type(4))) float f32x4;

constexpr int B_ = 4, S_ = 2048, D_ = 512, H_ = 8, DP_ = 64;
constexpr int M_ = B_ * S_;  // 8192 rows

__device__ __forceinline__ unsigned short f2b(float f) {
    __hip_bfloat16 h = __float2bfloat16(f);
    return *reinterpret_cast<unsigned short*>(&h);
}

__device__ __forceinline__ void gload_lds16(const unsigned short* g, unsigned short* l) {
    __builtin_amdgcn_global_load_lds((const __attribute__((address_space(1))) void*)g,
                                     (__attribute__((address_space(3))) void*)l, 16, 0, 0);
}

#define MFMA16(a, b, c) __builtin_amdgcn_mfma_f32_16x16x32_bf16((a), (b), (c), 0, 0, 0)

// ---------------- fp32 -> bf16 convert (x) ----------------
__global__ __launch_bounds__(256)
void convert_x(const float* __restrict__ in, unsigned short* __restrict__ out) {
    int i = blockIdx.x * 256 + threadIdx.x;   // one float4 per thread
    float4 v = ((const float4*)in)[i];
    ushort4 o;
    o.x = f2b(v.x); o.y = f2b(v.y); o.z = f2b(v.z); o.w = f2b(v.w);
    ((ushort4*)out)[i] = o;
}

// ---------------- weight transpose + convert: Wt[n][k] = bf16(W[k][n]) ----------------
__global__ __launch_bounds__(256)
void transpose_w(const float* __restrict__ w0, const float* __restrict__ w1,
                 const float* __restrict__ w2, const float* __restrict__ w3,
                 unsigned short* __restrict__ outw) {
    const float* in = (blockIdx.z == 0) ? w0 : (blockIdx.z == 1) ? w1
                     : (blockIdx.z == 2) ? w2 : w3;
    unsigned short* out = outw + (size_t)blockIdx.z * D_ * D_;
    __shared__ float t[64][65];
    int k0 = blockIdx.x * 64, n0 = blockIdx.y * 64;
    int tx = threadIdx.x & 63, ty = threadIdx.x >> 6;
#pragma unroll
    for (int i = 0; i < 16; i++) {
        int r = ty * 16 + i;
        t[r][tx] = in[(size_t)(k0 + r) * D_ + n0 + tx];
    }
    __syncthreads();
#pragma unroll
    for (int i = 0; i < 16; i++) {
        int r = ty * 16 + i;
        out[(size_t)(n0 + r) * D_ + k0 + tx] = f2b(t[tx][r]);
    }
}

// ---------------- QKV GEMM (Q,K only): [8192x512] @ W -> scatter to [B][H][S][64] ----------------
__global__ __launch_bounds__(256, 2)
void gemm_qkv(const unsigned short* __restrict__ X,
              const unsigned short* __restrict__ Wt,   // [2][512][512] transposed bf16
              unsigned short* __restrict__ QKV) {      // [2][B][H][S][64]
    const unsigned short* Bt = Wt + (size_t)blockIdx.z * D_ * D_;
    unsigned short* out = QKV + (size_t)blockIdx.z * M_ * D_;
    int m0 = blockIdx.x * 128, n0 = blockIdx.y * 128;
    int tid = threadIdx.x;
    int wave = tid >> 6, lane = tid & 63, l16 = lane & 15, quad = lane >> 4;
    int wm = (wave >> 1) * 64, wn = (wave & 1) * 64;

    __shared__ __align__(16) unsigned short As[128][40];
    __shared__ __align__(16) unsigned short Bs[128][40];

    f32x4 acc[4][4];
    const f32x4 zf = {0.f, 0.f, 0.f, 0.f};
#pragma unroll
    for (int i = 0; i < 4; i++)
#pragma unroll
        for (int j = 0; j < 4; j++) acc[i][j] = zf;

    for (int k0 = 0; k0 < D_; k0 += 32) {
        __syncthreads();
#pragma unroll
        for (int i = 0; i < 2; i++) {
            int c = tid + i * 256;
            int row = c >> 2, off = (c & 3) * 8;
            *(short8*)&As[row][off] = *(const short8*)(X + (size_t)(m0 + row) * D_ + k0 + off);
            *(short8*)&Bs[row][off] = *(const short8*)(Bt + (size_t)(n0 + row) * D_ + k0 + off);
        }
        __syncthreads();
        short8 af[4], bf[4];
#pragma unroll
        for (int mt = 0; mt < 4; mt++) af[mt] = *(const short8*)&As[wm + mt * 16 + l16][quad * 8];
#pragma unroll
        for (int nt = 0; nt < 4; nt++) bf[nt] = *(const short8*)&Bs[wn + nt * 16 + l16][quad * 8];
#pragma unroll
        for (int mt = 0; mt < 4; mt++)
#pragma unroll
            for (int nt = 0; nt < 4; nt++)
                acc[mt][nt] = MFMA16(af[mt], bf[nt], acc[mt][nt]);
    }
    // epilogue: C/D layout col=lane&15, row=quad*4+r; scatter to [B][H][S][64]
#pragma unroll
    for (int mt = 0; mt < 4; mt++)
#pragma unroll
        for (int nt = 0; nt < 4; nt++)
#pragma unroll
            for (int r = 0; r < 4; r++) {
                int m = m0 + wm + mt * 16 + quad * 4 + r;
                int n = n0 + wn + nt * 16 + l16;
                int bb = m >> 11, ss = m & 2047, hh = n >> 6, dd = n & 63;
                out[(((size_t)bb * H_ + hh) * S_ + ss) * DP_ + dd] = f2b(acc[mt][nt][r]);
            }
}

// ---------------- V^T GEMM: Vt_b = Wv^T (.) X_b^T  -> [B][512][2048] ----------------
// out[m][n] = sum_k Wv^T[m][k] * X[b*S+n][k] = V_b[n][m]  (coalesced along n=s)
__global__ __launch_bounds__(256, 2)
void gemm_vt(const unsigned short* __restrict__ X,
             const unsigned short* __restrict__ Wt,   // Wv^T [512][512] bf16
             unsigned short* __restrict__ Vt) {       // [B][D][S] bf16
    int bb = blockIdx.z;
    int m0 = blockIdx.x * 128, n0 = blockIdx.y * 128;
    int tid = threadIdx.x;
    int wave = tid >> 6, lane = tid & 63, l16 = lane & 15, quad = lane >> 4;
    int wm = (wave >> 1) * 64, wn = (wave & 1) * 64;

    __shared__ __align__(16) unsigned short As[128][40];
    __shared__ __align__(16) unsigned short Bs[128][40];

    f32x4 acc[4][4];
    const f32x4 zf = {0.f, 0.f, 0.f, 0.f};
#pragma unroll
    for (int i = 0; i < 4; i++)
#pragma unroll
        for (int j = 0; j < 4; j++) acc[i][j] = zf;

    for (int k0 = 0; k0 < D_; k0 += 32) {
        __syncthreads();
#pragma unroll
        for (int i = 0; i < 2; i++) {
            int c = tid + i * 256;
            int row = c >> 2, off = (c & 3) * 8;
            *(short8*)&As[row][off] = *(const short8*)(Wt + (size_t)(m0 + row) * D_ + k0 + off);
            *(short8*)&Bs[row][off] = *(const short8*)(X + (size_t)(bb * S_ + n0 + row) * D_ + k0 + off);
        }
        __syncthreads();
        short8 af[4], bf[4];
#pragma unroll
        for (int mt = 0; mt < 4; mt++) af[mt] = *(const short8*)&As[wm + mt * 16 + l16][quad * 8];
#pragma unroll
        for (int nt = 0; nt < 4; nt++) bf[nt] = *(const short8*)&Bs[wn + nt * 16 + l16][quad * 8];
#pragma unroll
        for (int mt = 0; mt < 4; mt++)
#pragma unroll
            for (int nt = 0; nt < 4; nt++)
                acc[mt][nt] = MFMA16(af[mt], bf[nt], acc[mt][nt]);
    }
#pragma unroll
    for (int mt = 0; mt < 4; mt++)
#pragma unroll
        for (int nt = 0; nt < 4; nt++)
#pragma unroll
            for (int r = 0; r < 4; r++) {
                int m = m0 + wm + mt * 16 + quad * 4 + r;   // d-row in [0,512)
                int n = n0 + wn + nt * 16 + l16;            // s in [0,2048)
                Vt[((size_t)bb * D_ + m) * S_ + n] = f2b(acc[mt][nt][r]);
            }
}

// ---------------- flash attention: per (b,h,64-q-rows) block, software-pipelined ----------------
// Swapped QK^T; K tile fully prefetched into registers (reloaded during PV); V tile
// staged via global_load_lds with XOR-swizzle; defer-max softmax.
// launch_bounds (256,3): 168-VGPR cap >= ~150 needed -- (256,4)'s 128 cap spilled
// the K-prefetch arrays to scratch (R4: WRITE_SIZE 420 MB of spill traffic).
__global__ __launch_bounds__(256, 3)
void flash_attn(const unsigned short* __restrict__ Qg, const unsigned short* __restrict__ Kg,
                const unsigned short* __restrict__ Vt, unsigned short* __restrict__ ctx) {
    int bid0 = blockIdx.x;
    int bid = (bid0 & 7) * 128 + (bid0 >> 3);   // XCD swizzle: 4 heads per XCD (1024 = 8*128)
    int qt = bid & 31, hh = (bid >> 5) & 7, bb = bid >> 8;
    int tid = threadIdx.x;
    int wave = tid >> 6, lane = tid & 63, l16 = lane & 15, quad = lane >> 4;
    int qh = quad >> 1, ql = quad & 1;

    size_t bh = ((size_t)bb * H_ + hh) * S_ * DP_;
    const unsigned short* Qb = Qg + bh;
    const unsigned short* Kb = Kg + bh;
    const unsigned short* Vb = Vt + bh;   // V^T head slice: 64 rows (d), 2048 cols (s)

    // V^T tile [64 d][128 s] bf16, UNPADDED, chunk-XOR swizzled: 16B chunk at
    // physical index p holds logical chunk p ^ (row&7). Written linearly by
    // global_load_lds from an inverse-swizzled global address (m201/m231 pattern).
    __shared__ __align__(16) unsigned short Vts[64][128];
    // per-wave P tile [16 q][128 k], chunk-XOR swizzle (proven R3)
    __shared__ __align__(16) unsigned short Ps[4][16][128];

    const int psw = l16 & 7;
    const int vrow = 4 * wave + (lane >> 4);   // V-staging row (+16*i)

    // Q fragments in registers for the whole kernel
    short8 qf0, qf1;
    {
        const unsigned short* qp = Qb + (size_t)(qt * 64 + wave * 16 + l16) * DP_ + quad * 8;
        qf0 = *(const short8*)qp;
        qf1 = *(const short8*)(qp + 32);
    }

    // prologue: issue V tile 0 DMA + load K tile 0 into registers
#pragma unroll
    for (int i = 0; i < 4; i++) {
        int row = vrow + 16 * i;
        int lc = (lane & 15) ^ (row & 7);
        gload_lds16(Vb + (size_t)row * S_ + lc * 8, &Vts[16 * i + 4 * wave][0]);
    }
    short8 kf0[8], kf1[8];
#pragma unroll
    for (int nt = 0; nt < 8; nt++) {
        const unsigned short* kp = Kb + (size_t)(nt * 16 + l16) * DP_ + quad * 8;
        kf0[nt] = *(const short8*)kp;
        kf1[nt] = *(const short8*)(kp + 32);
    }

    const f32x4 zf = {0.f, 0.f, 0.f, 0.f};
    f32x4 oacc[4];
#pragma unroll
    for (int i = 0; i < 4; i++) oacc[i] = zf;
    float m2 = -1e30f;   // running max offset in log2 domain (possibly stale: defer-max)
    float lrow = 0.f;
    constexpr float c1 = 0.125f * 1.44269504088896f;  // (1/sqrt(64)) * log2(e)

    for (int kv = 0; kv < S_; kv += 128) {
        int kvn = kv + 128;

        // (1) S^T = K Q^T entirely from registers: sacc[nt][r] = S[q=l16][k=16nt+4quad+r]
        __builtin_amdgcn_s_setprio(1);
        f32x4 sacc[8];
#pragma unroll
        for (int nt = 0; nt < 8; nt++) {
            f32x4 s = zf;
            s = MFMA16(kf0[nt], qf0, s);
            s = MFMA16(kf1[nt], qf1, s);
            sacc[nt] = s;
        }
        __builtin_amdgcn_s_setprio(0);

        // (2) defer-max online softmax (lane-local row q = l16), Ps writes (per-wave)
        float t8[8];
#pragma unroll
        for (int nt = 0; nt < 8; nt++)
            t8[nt] = fmaxf(fmaxf(sacc[nt][0], sacc[nt][1]), fmaxf(sacc[nt][2], sacc[nt][3]));
        float g = fmaxf(fmaxf(fmaxf(t8[0], t8[1]), fmaxf(t8[2], t8[3])),
                        fmaxf(fmaxf(t8[4], t8[5]), fmaxf(t8[6], t8[7])));
        g = fmaxf(g, __shfl_xor(g, 16));
        g = fmaxf(g, __shfl_xor(g, 32));
        g *= c1;
        float alpha = 1.0f;
        bool need = !__all(g <= m2 + 8.0f);
        if (need) {
            float m2n = fmaxf(m2, g);
            alpha = __builtin_amdgcn_exp2f(m2 - m2n);
            m2 = m2n;
        }
        float rs = 0.f;
#pragma unroll
        for (int nt = 0; nt < 8; nt++) {
            float p0 = __builtin_amdgcn_exp2f(__builtin_fmaf(sacc[nt][0], c1, -m2));
            float p1 = __builtin_amdgcn_exp2f(__builtin_fmaf(sacc[nt][1], c1, -m2));
            float p2 = __builtin_amdgcn_exp2f(__builtin_fmaf(sacc[nt][2], c1, -m2));
            float p3 = __builtin_amdgcn_exp2f(__builtin_fmaf(sacc[nt][3], c1, -m2));
            rs += (p0 + p1) + (p2 + p3);
            ushort4 pk;
            pk.x = f2b(p0); pk.y = f2b(p1); pk.z = f2b(p2); pk.w = f2b(p3);
            int c8 = (2 * nt + qh) ^ psw;
            *(ushort4*)&Ps[wave][l16][c8 * 8 + 4 * ql] = pk;
        }
        rs += __shfl_xor(rs, 16);
        rs += __shfl_xor(rs, 32);
        lrow = alpha * lrow + rs;
        if (need) {
            float al0 = __shfl(alpha, quad * 4 + 0);
            float al1 = __shfl(alpha, quad * 4 + 1);
            float al2 = __shfl(alpha, quad * 4 + 2);
            float al3 = __shfl(alpha, quad * 4 + 3);
#pragma unroll
            for (int ot = 0; ot < 4; ot++) {
                oacc[ot][0] *= al0; oacc[ot][1] *= al1;
                oacc[ot][2] *= al2; oacc[ot][3] *= al3;
            }
        }

        // (3) barrier: V DMA (issued last iter) drained by the implicit vmcnt(0);
        //     also orders all waves past the previous PV reads.
        __syncthreads();

        // (4) K prefetch for next iter (lands under PV + next barrier), then PV
        if (kvn < S_) {
#pragma unroll
            for (int nt = 0; nt < 8; nt++) {
                const unsigned short* kp = Kb + (size_t)(kvn + nt * 16 + l16) * DP_ + quad * 8;
                kf0[nt] = *(const short8*)kp;
                kf1[nt] = *(const short8*)(kp + 32);
            }
        }
        __builtin_amdgcn_s_setprio(1);
#pragma unroll
        for (int kt = 0; kt < 4; kt++) {
            int pc = ((4 * kt + quad) ^ psw) * 8;   // same swizzled chunk for Ps AND Vts
            short8 pf = *(const short8*)&Ps[wave][l16][pc];
#pragma unroll
            for (int ot = 0; ot < 4; ot++) {
                short8 vf = *(const short8*)&Vts[ot * 16 + l16][pc];
                oacc[ot] = MFMA16(pf, vf, oacc[ot]);
            }
        }
        __builtin_amdgcn_s_setprio(0);

        // (5) all waves done reading Vts tile
        __syncthreads();

        // (6) issue next V tile DMA (in flight across next QK + softmax)
        if (kvn < S_) {
#pragma unroll
            for (int i = 0; i < 4; i++) {
                int row = vrow + 16 * i;
                int lc = (lane & 15) ^ (row & 7);
                gload_lds16(Vb + (size_t)row * S_ + kvn + lc * 8, &Vts[16 * i + 4 * wave][0]);
            }
        }
    }
    // epilogue: normalize (l for row q=quad*4+r via shfl), merge heads into [B][S][512]
    float lb0 = __shfl(lrow, quad * 4 + 0);
    float lb1 = __shfl(lrow, quad * 4 + 1);
    float lb2 = __shfl(lrow, quad * 4 + 2);
    float lb3 = __shfl(lrow, quad * 4 + 3);
    float iv0 = __builtin_amdgcn_rcpf(lb0);
    float iv1 = __builtin_amdgcn_rcpf(lb1);
    float iv2 = __builtin_amdgcn_rcpf(lb2);
    float iv3 = __builtin_amdgcn_rcpf(lb3);
#pragma unroll
    for (int ot = 0; ot < 4; ot++) {
        int srow0 = qt * 64 + wave * 16 + quad * 4;
        size_t base = ((size_t)bb * S_ + srow0) * D_ + hh * DP_ + ot * 16 + l16;
        ctx[base]          = f2b(oacc[ot][0] * iv0);
        ctx[base + D_]     = f2b(oacc[ot][1] * iv1);
        ctx[base + 2 * D_] = f2b(oacc[ot][2] * iv2);
        ctx[base + 3 * D_] = f2b(oacc[ot][3] * iv3);
    }
}

// ---------------- output projection GEMM -> fp32 scratch ----------------
__global__ __launch_bounds__(256, 2)
void gemm_proj(const unsigned short* __restrict__ A,   // ctx [8192][512] bf16
               const unsigned short* __restrict__ Bt,  // Wo^T [512][512] bf16
               float* __restrict__ outf) {             // [8192][512] fp32
    int m0 = blockIdx.x * 128, n0 = blockIdx.y * 128;
    int tid = threadIdx.x;
    int wave = tid >> 6, lane = tid & 63, l16 = lane & 15, quad = lane >> 4;
    int wm = (wave >> 1) * 64, wn = (wave & 1) * 64;

    __shared__ __align__(16) unsigned short As[128][40];
    __shared__ __align__(16) unsigned short Bs[128][40];

    f32x4 acc[4][4];
    const f32x4 zf = {0.f, 0.f, 0.f, 0.f};
#pragma unroll
    for (int i = 0; i < 4; i++)
#pragma unroll
        for (int j = 0; j < 4; j++) acc[i][j] = zf;

    for (int k0 = 0; k0 < D_; k0 += 32) {
        __syncthreads();
#pragma unroll
        for (int i = 0; i < 2; i++) {
            int c = tid + i * 256;
            int row = c >> 2, off = (c & 3) * 8;
            *(short8*)&As[row][off] = *(const short8*)(A + (size_t)(m0 + row) * D_ + k0 + off);
            *(short8*)&Bs[row][off] = *(const short8*)(Bt + (size_t)(n0 + row) * D_ + k0 + off);
        }
        __syncthreads();
        short8 af[4], bf[4];
#pragma unroll
        for (int mt = 0; mt < 4; mt++) af[mt] = *(const short8*)&As[wm + mt * 16 + l16][quad * 8];
#pragma unroll
        for (int nt = 0; nt < 4; nt++) bf[nt] = *(const short8*)&Bs[wn + nt * 16 + l16][quad * 8];
#pragma unroll
        for (int mt = 0; mt < 4; mt++)
#pragma unroll
            for (int nt = 0; nt < 4; nt++)
                acc[mt][nt] = MFMA16(af[mt], bf[nt], acc[mt][nt]);
    }
#pragma unroll
    for (int mt = 0; mt < 4; mt++)
#pragma unroll
        for (int nt = 0; nt < 4; nt++)
#pragma unroll
            for (int r = 0; r < 4; r++) {
                int m = m0 + wm + mt * 16 + quad * 4 + r;
                int n = n0 + wn + nt * 16 + l16;
                outf[(size_t)m * D_ + n] = acc[mt][nt][r];
            }
}

// ---------------- bias + residual + LayerNorm (all fp32), one block per row ----------------
__global__ __launch_bounds__(256, 4)
void ln_out(const float* __restrict__ tmp, const float* __restrict__ Xg,
            const float* __restrict__ bo, const float* __restrict__ gamma,
            const float* __restrict__ beta, float* __restrict__ outp) {
    int row = blockIdx.x;
    int tid = threadIdx.x;
    int lane = tid & 63, wave = tid >> 6;
    float resid[2];
#pragma unroll
    for (int i = 0; i < 2; i++) {
        int c = tid + i * 256;
        resid[i] = Xg[(size_t)row * D_ + c] + tmp[(size_t)row * D_ + c] + bo[c];
    }
    float sum = resid[0] + resid[1];
    float sq = resid[0] * resid[0] + resid[1] * resid[1];
#pragma unroll
    for (int off = 1; off < 64; off <<= 1) {
        sum += __shfl_xor(sum, off);
        sq += __shfl_xor(sq, off);
    }
    __shared__ float red[8];
    if (lane == 0) { red[wave] = sum; red[4 + wave] = sq; }
    __syncthreads();
    sum = red[0] + red[1] + red[2] + red[3];
    sq = red[4] + red[5] + red[6] + red[7];
    float mu = sum * (1.0f / D_);
    float var = sq * (1.0f / D_) - mu * mu;
    float rstd = rsqrtf(var + 1e-6f);
#pragma unroll
    for (int i = 0; i < 2; i++) {
        int c = tid + i * 256;
        float o = (resid[i] - mu) * rstd * gamma[c] + beta[c];
        outp[(size_t)row * D_ + c] = o;
    }
}

extern "C" void kernel_launch(void* const* d_in, const int* in_sizes, int n_in,
                              void* d_out, int out_size, void* d_ws, size_t ws_size,
                              hipStream_t stream) {
    const float* x     = (const float*)d_in[0];
    const float* wq    = (const float*)d_in[1];
    const float* wk    = (const float*)d_in[2];
    const float* wv    = (const float*)d_in[3];
    const float* wo    = (const float*)d_in[4];
    const float* bo    = (const float*)d_in[5];
    const float* gamma = (const float*)d_in[6];
    const float* beta  = (const float*)d_in[7];
    float* out = (float*)d_out;

    // ws layout (bf16 elems unless noted), total 34 MB:
    //   [xb 8MB | wt 2MB | Q,K,Vt 24MB]
    //   ctx aliases xb (xb dead after the projection GEMMs). fp32 tmp aliases Q (dead after flash).
    unsigned short* xb  = (unsigned short*)d_ws;                    // 8192*512 bf16
    unsigned short* wt  = xb + (size_t)M_ * D_;                     // 4*512*512 bf16
    unsigned short* Q   = wt + 4 * D_ * D_;
    unsigned short* K   = Q + (size_t)M_ * D_;
    unsigned short* Vt  = K + (size_t)M_ * D_;                      // [B][512][2048]
    unsigned short* ctx = xb;                                       // alias: xb dead
    float* tmp = (float*)Q;                                         // alias: Q/K/Vt dead

    convert_x<<<dim3(M_ * D_ / 4 / 256), 256, 0, stream>>>(x, xb);
    transpose_w<<<dim3(8, 8, 4), 256, 0, stream>>>(wq, wk, wv, wo, wt);
    gemm_qkv<<<dim3(64, 4, 2), 256, 0, stream>>>(xb, wt, Q);
    gemm_vt<<<dim3(4, 16, 4), 256, 0, stream>>>(xb, wt + 2 * (size_t)D_ * D_, Vt);
    flash_attn<<<dim3(1024), 256, 0, stream>>>(Q, K, Vt, ctx);
    gemm_proj<<<dim3(64, 4), 256, 0, stream>>>(ctx, wt + 3 * (size_t)D_ * D_, tmp);
    ln_out<<<dim3(8192), 256, 0, stream>>>(tmp, x, bo, gamma, beta, out);
}

// Round 6
// 199.786 us; speedup vs baseline: 1.8042x; 1.3735x over previous
//
#include <hip/hip_runtime.h>
#include <hip/hip_bf16.h>

typedef __attribute__((ext_vector_type(8))) short short8;
typedef __attribute__((ext_vector_type(4))) float f32x4;

constexpr int B_ = 4, S_ = 2048, D_ = 512, H_ = 8, DP_ = 64;
constexpr int M_ = B_ * S_;  // 8192 rows

__device__ __forceinline__ unsigned short f2b(float f) {
    __hip_bfloat16 h = __float2bfloat16(f);
    return *reinterpret_cast<unsigned short*>(&h);
}

__device__ __forceinline__ void gload_lds16(const unsigned short* g, unsigned short* l) {
    __builtin_amdgcn_global_load_lds((const __attribute__((address_space(1))) void*)g,
                                     (__attribute__((address_space(3))) void*)l, 16, 0, 0);
}

#define MFMA16(a, b, c) __builtin_amdgcn_mfma_f32_16x16x32_bf16((a), (b), (c), 0, 0, 0)
#define ASM_BAR() asm volatile("s_barrier" ::: "memory")

// ---------------- fp32 -> bf16 convert (x) ----------------
__global__ __launch_bounds__(256)
void convert_x(const float* __restrict__ in, unsigned short* __restrict__ out) {
    int i = blockIdx.x * 256 + threadIdx.x;   // one float4 per thread
    float4 v = ((const float4*)in)[i];
    ushort4 o;
    o.x = f2b(v.x); o.y = f2b(v.y); o.z = f2b(v.z); o.w = f2b(v.w);
    ((ushort4*)out)[i] = o;
}

// ---------------- weight transpose + convert: Wt[n][k] = bf16(W[k][n]) ----------------
__global__ __launch_bounds__(256)
void transpose_w(const float* __restrict__ w0, const float* __restrict__ w1,
                 const float* __restrict__ w2, const float* __restrict__ w3,
                 unsigned short* __restrict__ outw) {
    const float* in = (blockIdx.z == 0) ? w0 : (blockIdx.z == 1) ? w1
                     : (blockIdx.z == 2) ? w2 : w3;
    unsigned short* out = outw + (size_t)blockIdx.z * D_ * D_;
    __shared__ float t[64][65];
    int k0 = blockIdx.x * 64, n0 = blockIdx.y * 64;
    int tx = threadIdx.x & 63, ty = threadIdx.x >> 6;
#pragma unroll
    for (int i = 0; i < 16; i++) {
        int r = ty * 16 + i;
        t[r][tx] = in[(size_t)(k0 + r) * D_ + n0 + tx];
    }
    __syncthreads();
#pragma unroll
    for (int i = 0; i < 16; i++) {
        int r = ty * 16 + i;
        out[(size_t)(n0 + r) * D_ + k0 + tx] = f2b(t[tx][r]);
    }
}

// ---------------- QKV GEMM (Q,K only): [8192x512] @ W -> scatter to [B][H][S][64] ----------------
__global__ __launch_bounds__(256, 2)
void gemm_qkv(const unsigned short* __restrict__ X,
              const unsigned short* __restrict__ Wt,   // [2][512][512] transposed bf16
              unsigned short* __restrict__ QKV) {      // [2][B][H][S][64]
    const unsigned short* Bt = Wt + (size_t)blockIdx.z * D_ * D_;
    unsigned short* out = QKV + (size_t)blockIdx.z * M_ * D_;
    int m0 = blockIdx.x * 128, n0 = blockIdx.y * 128;
    int tid = threadIdx.x;
    int wave = tid >> 6, lane = tid & 63, l16 = lane & 15, quad = lane >> 4;
    int wm = (wave >> 1) * 64, wn = (wave & 1) * 64;

    __shared__ __align__(16) unsigned short As[128][40];
    __shared__ __align__(16) unsigned short Bs[128][40];

    f32x4 acc[4][4];
    const f32x4 zf = {0.f, 0.f, 0.f, 0.f};
#pragma unroll
    for (int i = 0; i < 4; i++)
#pragma unroll
        for (int j = 0; j < 4; j++) acc[i][j] = zf;

    for (int k0 = 0; k0 < D_; k0 += 32) {
        __syncthreads();
#pragma unroll
        for (int i = 0; i < 2; i++) {
            int c = tid + i * 256;
            int row = c >> 2, off = (c & 3) * 8;
            *(short8*)&As[row][off] = *(const short8*)(X + (size_t)(m0 + row) * D_ + k0 + off);
            *(short8*)&Bs[row][off] = *(const short8*)(Bt + (size_t)(n0 + row) * D_ + k0 + off);
        }
        __syncthreads();
        short8 af[4], bf[4];
#pragma unroll
        for (int mt = 0; mt < 4; mt++) af[mt] = *(const short8*)&As[wm + mt * 16 + l16][quad * 8];
#pragma unroll
        for (int nt = 0; nt < 4; nt++) bf[nt] = *(const short8*)&Bs[wn + nt * 16 + l16][quad * 8];
#pragma unroll
        for (int mt = 0; mt < 4; mt++)
#pragma unroll
            for (int nt = 0; nt < 4; nt++)
                acc[mt][nt] = MFMA16(af[mt], bf[nt], acc[mt][nt]);
    }
    // epilogue: C/D layout col=lane&15, row=quad*4+r; scatter to [B][H][S][64]
#pragma unroll
    for (int mt = 0; mt < 4; mt++)
#pragma unroll
        for (int nt = 0; nt < 4; nt++)
#pragma unroll
            for (int r = 0; r < 4; r++) {
                int m = m0 + wm + mt * 16 + quad * 4 + r;
                int n = n0 + wn + nt * 16 + l16;
                int bb = m >> 11, ss = m & 2047, hh = n >> 6, dd = n & 63;
                out[(((size_t)bb * H_ + hh) * S_ + ss) * DP_ + dd] = f2b(acc[mt][nt][r]);
            }
}

// ---------------- V^T GEMM: Vt_b = Wv^T (.) X_b^T  -> [B][512][2048] ----------------
__global__ __launch_bounds__(256, 2)
void gemm_vt(const unsigned short* __restrict__ X,
             const unsigned short* __restrict__ Wt,   // Wv^T [512][512] bf16
             unsigned short* __restrict__ Vt) {       // [B][D][S] bf16
    int bb = blockIdx.z;
    int m0 = blockIdx.x * 128, n0 = blockIdx.y * 128;
    int tid = threadIdx.x;
    int wave = tid >> 6, lane = tid & 63, l16 = lane & 15, quad = lane >> 4;
    int wm = (wave >> 1) * 64, wn = (wave & 1) * 64;

    __shared__ __align__(16) unsigned short As[128][40];
    __shared__ __align__(16) unsigned short Bs[128][40];

    f32x4 acc[4][4];
    const f32x4 zf = {0.f, 0.f, 0.f, 0.f};
#pragma unroll
    for (int i = 0; i < 4; i++)
#pragma unroll
        for (int j = 0; j < 4; j++) acc[i][j] = zf;

    for (int k0 = 0; k0 < D_; k0 += 32) {
        __syncthreads();
#pragma unroll
        for (int i = 0; i < 2; i++) {
            int c = tid + i * 256;
            int row = c >> 2, off = (c & 3) * 8;
            *(short8*)&As[row][off] = *(const short8*)(Wt + (size_t)(m0 + row) * D_ + k0 + off);
            *(short8*)&Bs[row][off] = *(const short8*)(X + (size_t)(bb * S_ + n0 + row) * D_ + k0 + off);
        }
        __syncthreads();
        short8 af[4], bf[4];
#pragma unroll
        for (int mt = 0; mt < 4; mt++) af[mt] = *(const short8*)&As[wm + mt * 16 + l16][quad * 8];
#pragma unroll
        for (int nt = 0; nt < 4; nt++) bf[nt] = *(const short8*)&Bs[wn + nt * 16 + l16][quad * 8];
#pragma unroll
        for (int mt = 0; mt < 4; mt++)
#pragma unroll
            for (int nt = 0; nt < 4; nt++)
                acc[mt][nt] = MFMA16(af[mt], bf[nt], acc[mt][nt]);
    }
#pragma unroll
    for (int mt = 0; mt < 4; mt++)
#pragma unroll
        for (int nt = 0; nt < 4; nt++)
#pragma unroll
            for (int r = 0; r < 4; r++) {
                int m = m0 + wm + mt * 16 + quad * 4 + r;   // d-row in [0,512)
                int n = n0 + wn + nt * 16 + l16;            // s in [0,2048)
                Vt[((size_t)bb * D_ + m) * S_ + n] = f2b(acc[mt][nt][r]);
            }
}

// ---------------- flash attention: K AND V DMA-staged, double-buffered, counted vmcnt ----
// KVBLK=64. Nothing bulky lives in registers across barriers (R4 spilled at cap 128,
// R5's compiler sank the "register K prefetch" back to its use at VGPR=84 -- so the
// tiles live in LDS, streamed by global_load_lds, tile t+1 always in flight (vmcnt(4),
// never 0 mid-loop). All LDS tiles chunk-XOR swizzled (chunk ^= row&7) with
// inverse-swizzled DMA global source + linear LDS dest (both-sides rule).
__global__ __launch_bounds__(256, 4)
void flash_attn(const unsigned short* __restrict__ Qg, const unsigned short* __restrict__ Kg,
                const unsigned short* __restrict__ Vt, unsigned short* __restrict__ ctx) {
    int bid0 = blockIdx.x;
    int bid = (bid0 & 7) * 128 + (bid0 >> 3);   // XCD swizzle: 4 heads per XCD (1024 = 8*128)
    int qt = bid & 31, hh = (bid >> 5) & 7, bb = bid >> 8;
    int tid = threadIdx.x;
    int wave = tid >> 6, lane = tid & 63, l16 = lane & 15, quad = lane >> 4;
    int qh = quad >> 1, ql = quad & 1;

    size_t bh = ((size_t)bb * H_ + hh) * S_ * DP_;
    const unsigned short* Qb = Qg + bh;
    const unsigned short* Kb = Kg + bh;
    const unsigned short* Vb = Vt + bh;   // V^T head slice: 64 rows (d), 2048 cols (s)

    // 40960 B total -> exactly 4 blocks/CU
    __shared__ __align__(16) unsigned short Kls[2][64][64];  // [buf][key s][d]
    __shared__ __align__(16) unsigned short Vls[2][64][64];  // [buf][d][key s]
    __shared__ __align__(16) unsigned short Ps[4][16][64];   // per-wave P

    const int psw = l16 & 7;                       // read-side row XOR
    const int drow = (lane >> 3) & 7;              // DMA row-within-8-group
    const int dsw = (lane & 7) ^ drow;             // DMA inverse-swizzled source chunk

    // Q fragments in registers for the whole kernel
    short8 qf0, qf1;
    {
        const unsigned short* qp = Qb + (size_t)(qt * 64 + wave * 16 + l16) * DP_ + quad * 8;
        qf0 = *(const short8*)qp;
        qf1 = *(const short8*)(qp + 32);
    }

    // stage tile at kv into buffer b: 4 global_load_lds per wave (2 K + 2 V),
    // each writes 1KB (8 rows x 128B) linearly; source pre-swizzled per lane.
    auto stage = [&](int kv, int b) {
#pragma unroll
        for (int j = 0; j < 2; j++) {
            int r8 = (wave * 2 + j) * 8;
            int r = r8 + drow;
            gload_lds16(Kb + (size_t)(kv + r) * DP_ + dsw * 8, &Kls[b][r8][0]);
            gload_lds16(Vb + (size_t)r * S_ + kv + dsw * 8,    &Vls[b][r8][0]);
        }
    };

    // prologue: tiles 0 and 1 in flight; wait tile 0 only
    stage(0, 0);
    stage(64, 1);
    asm volatile("s_waitcnt vmcnt(4)" ::: "memory");
    ASM_BAR();

    const f32x4 zf = {0.f, 0.f, 0.f, 0.f};
    f32x4 oacc[4];
#pragma unroll
    for (int i = 0; i < 4; i++) oacc[i] = zf;
    float m2 = -1e30f;   // running max in log2 domain (possibly stale: defer-max)
    float lrow = 0.f;
    constexpr float c1 = 0.125f * 1.44269504088896f;  // (1/sqrt(64)) * log2(e)

    int cur = 0;
    for (int t = 0; t < 32; t++) {
        // (1) S^T = K Q^T from Kls[cur]: sacc[nt][r] = S[q=l16][k=16nt+4quad+r]
        __builtin_amdgcn_s_setprio(1);
        f32x4 sacc[4];
#pragma unroll
        for (int nt = 0; nt < 4; nt++) {
            const unsigned short* kr = &Kls[cur][nt * 16 + l16][0];
            short8 kf0 = *(const short8*)(kr + ((quad ^ psw) * 8));
            short8 kf1 = *(const short8*)(kr + (((quad ^ 4) ^ psw) * 8));
            f32x4 s = zf;
            s = MFMA16(kf0, qf0, s);
            s = MFMA16(kf1, qf1, s);
            sacc[nt] = s;
        }
        __builtin_amdgcn_s_setprio(0);

        // (2) defer-max online softmax (lane-local row q=l16, 16 values)
        float t4[4];
#pragma unroll
        for (int nt = 0; nt < 4; nt++)
            t4[nt] = fmaxf(fmaxf(sacc[nt][0], sacc[nt][1]), fmaxf(sacc[nt][2], sacc[nt][3]));
        float g = fmaxf(fmaxf(t4[0], t4[1]), fmaxf(t4[2], t4[3]));
        g = fmaxf(g, __shfl_xor(g, 16));
        g = fmaxf(g, __shfl_xor(g, 32));
        g *= c1;
        float alpha = 1.0f;
        bool need = !__all(g <= m2 + 8.0f);
        if (need) {
            float m2n = fmaxf(m2, g);
            alpha = __builtin_amdgcn_exp2f(m2 - m2n);
            m2 = m2n;
        }
        float rs = 0.f;
#pragma unroll
        for (int nt = 0; nt < 4; nt++) {
            float p0 = __builtin_amdgcn_exp2f(__builtin_fmaf(sacc[nt][0], c1, -m2));
            float p1 = __builtin_amdgcn_exp2f(__builtin_fmaf(sacc[nt][1], c1, -m2));
            float p2 = __builtin_amdgcn_exp2f(__builtin_fmaf(sacc[nt][2], c1, -m2));
            float p3 = __builtin_amdgcn_exp2f(__builtin_fmaf(sacc[nt][3], c1, -m2));
            rs += (p0 + p1) + (p2 + p3);
            ushort4 pk;
            pk.x = f2b(p0); pk.y = f2b(p1); pk.z = f2b(p2); pk.w = f2b(p3);
            int c8 = (2 * nt + qh) ^ psw;
            *(ushort4*)&Ps[wave][l16][c8 * 8 + 4 * ql] = pk;
        }
        rs += __shfl_xor(rs, 16);
        rs += __shfl_xor(rs, 32);
        lrow = alpha * lrow + rs;
        if (need) {
            float al0 = __shfl(alpha, quad * 4 + 0);
            float al1 = __shfl(alpha, quad * 4 + 1);
            float al2 = __shfl(alpha, quad * 4 + 2);
            float al3 = __shfl(alpha, quad * 4 + 3);
#pragma unroll
            for (int ot = 0; ot < 4; ot++) {
                oacc[ot][0] *= al0; oacc[ot][1] *= al1;
                oacc[ot][2] *= al2; oacc[ot][3] *= al3;
            }
        }

        // (3) O += P V from Ps + Vls[cur]
        __builtin_amdgcn_s_setprio(1);
#pragma unroll
        for (int kt = 0; kt < 2; kt++) {
            int pc = ((kt * 4 + quad) ^ psw) * 8;   // same swizzled chunk for Ps AND Vls
            short8 pf = *(const short8*)&Ps[wave][l16][pc];
#pragma unroll
            for (int ot = 0; ot < 4; ot++) {
                short8 vf = *(const short8*)&Vls[cur][ot * 16 + l16][pc];
                oacc[ot] = MFMA16(pf, vf, oacc[ot]);
            }
        }
        __builtin_amdgcn_s_setprio(0);

        // (4) all waves done reading buf[cur] -> refill it with tile t+2;
        //     wait tile t+1 (4 loads) only -- t+2 stays in flight across next iter.
        ASM_BAR();
        if (t < 30) {
            stage((t + 2) * 64, cur);
            asm volatile("s_waitcnt vmcnt(4)" ::: "memory");
        } else {
            asm volatile("s_waitcnt vmcnt(0)" ::: "memory");
        }
        ASM_BAR();
        cur ^= 1;
    }

    // epilogue: normalize (l for row q=quad*4+r via shfl), merge heads into [B][S][512]
    float lb0 = __shfl(lrow, quad * 4 + 0);
    float lb1 = __shfl(lrow, quad * 4 + 1);
    float lb2 = __shfl(lrow, quad * 4 + 2);
    float lb3 = __shfl(lrow, quad * 4 + 3);
    float iv0 = __builtin_amdgcn_rcpf(lb0);
    float iv1 = __builtin_amdgcn_rcpf(lb1);
    float iv2 = __builtin_amdgcn_rcpf(lb2);
    float iv3 = __builtin_amdgcn_rcpf(lb3);
#pragma unroll
    for (int ot = 0; ot < 4; ot++) {
        int srow0 = qt * 64 + wave * 16 + quad * 4;
        size_t base = ((size_t)bb * S_ + srow0) * D_ + hh * DP_ + ot * 16 + l16;
        ctx[base]          = f2b(oacc[ot][0] * iv0);
        ctx[base + D_]     = f2b(oacc[ot][1] * iv1);
        ctx[base + 2 * D_] = f2b(oacc[ot][2] * iv2);
        ctx[base + 3 * D_] = f2b(oacc[ot][3] * iv3);
    }
}

// ---------------- output projection GEMM -> fp32 scratch ----------------
__global__ __launch_bounds__(256, 2)
void gemm_proj(const unsigned short* __restrict__ A,   // ctx [8192][512] bf16
               const unsigned short* __restrict__ Bt,  // Wo^T [512][512] bf16
               float* __restrict__ outf) {             // [8192][512] fp32
    int m0 = blockIdx.x * 128, n0 = blockIdx.y * 128;
    int tid = threadIdx.x;
    int wave = tid >> 6, lane = tid & 63, l16 = lane & 15, quad = lane >> 4;
    int wm = (wave >> 1) * 64, wn = (wave & 1) * 64;

    __shared__ __align__(16) unsigned short As[128][40];
    __shared__ __align__(16) unsigned short Bs[128][40];

    f32x4 acc[4][4];
    const f32x4 zf = {0.f, 0.f, 0.f, 0.f};
#pragma unroll
    for (int i = 0; i < 4; i++)
#pragma unroll
        for (int j = 0; j < 4; j++) acc[i][j] = zf;

    for (int k0 = 0; k0 < D_; k0 += 32) {
        __syncthreads();
#pragma unroll
        for (int i = 0; i < 2; i++) {
            int c = tid + i * 256;
            int row = c >> 2, off = (c & 3) * 8;
            *(short8*)&As[row][off] = *(const short8*)(A + (size_t)(m0 + row) * D_ + k0 + off);
            *(short8*)&Bs[row][off] = *(const short8*)(Bt + (size_t)(n0 + row) * D_ + k0 + off);
        }
        __syncthreads();
        short8 af[4], bf[4];
#pragma unroll
        for (int mt = 0; mt < 4; mt++) af[mt] = *(const short8*)&As[wm + mt * 16 + l16][quad * 8];
#pragma unroll
        for (int nt = 0; nt < 4; nt++) bf[nt] = *(const short8*)&Bs[wn + nt * 16 + l16][quad * 8];
#pragma unroll
        for (int mt = 0; mt < 4; mt++)
#pragma unroll
            for (int nt = 0; nt < 4; nt++)
                acc[mt][nt] = MFMA16(af[mt], bf[nt], acc[mt][nt]);
    }
#pragma unroll
    for (int mt = 0; mt < 4; mt++)
#pragma unroll
        for (int nt = 0; nt < 4; nt++)
#pragma unroll
            for (int r = 0; r < 4; r++) {
                int m = m0 + wm + mt * 16 + quad * 4 + r;
                int n = n0 + wn + nt * 16 + l16;
                outf[(size_t)m * D_ + n] = acc[mt][nt][r];
            }
}

// ---------------- bias + residual + LayerNorm (all fp32), one block per row ----------------
__global__ __launch_bounds__(256, 4)
void ln_out(const float* __restrict__ tmp, const float* __restrict__ Xg,
            const float* __restrict__ bo, const float* __restrict__ gamma,
            const float* __restrict__ beta, float* __restrict__ outp) {
    int row = blockIdx.x;
    int tid = threadIdx.x;
    int lane = tid & 63, wave = tid >> 6;
    float resid[2];
#pragma unroll
    for (int i = 0; i < 2; i++) {
        int c = tid + i * 256;
        resid[i] = Xg[(size_t)row * D_ + c] + tmp[(size_t)row * D_ + c] + bo[c];
    }
    float sum = resid[0] + resid[1];
    float sq = resid[0] * resid[0] + resid[1] * resid[1];
#pragma unroll
    for (int off = 1; off < 64; off <<= 1) {
        sum += __shfl_xor(sum, off);
        sq += __shfl_xor(sq, off);
    }
    __shared__ float red[8];
    if (lane == 0) { red[wave] = sum; red[4 + wave] = sq; }
    __syncthreads();
    sum = red[0] + red[1] + red[2] + red[3];
    sq = red[4] + red[5] + red[6] + red[7];
    float mu = sum * (1.0f / D_);
    float var = sq * (1.0f / D_) - mu * mu;
    float rstd = rsqrtf(var + 1e-6f);
#pragma unroll
    for (int i = 0; i < 2; i++) {
        int c = tid + i * 256;
        float o = (resid[i] - mu) * rstd * gamma[c] + beta[c];
        outp[(size_t)row * D_ + c] = o;
    }
}

extern "C" void kernel_launch(void* const* d_in, const int* in_sizes, int n_in,
                              void* d_out, int out_size, void* d_ws, size_t ws_size,
                              hipStream_t stream) {
    const float* x     = (const float*)d_in[0];
    const float* wq    = (const float*)d_in[1];
    const float* wk    = (const float*)d_in[2];
    const float* wv    = (const float*)d_in[3];
    const float* wo    = (const float*)d_in[4];
    const float* bo    = (const float*)d_in[5];
    const float* gamma = (const float*)d_in[6];
    const float* beta  = (const float*)d_in[7];
    float* out = (float*)d_out;

    // ws layout (bf16 elems unless noted), total 34 MB:
    //   [xb 8MB | wt 2MB | Q,K,Vt 24MB]
    //   ctx aliases xb (xb dead after the projection GEMMs). fp32 tmp aliases Q (dead after flash).
    unsigned short* xb  = (unsigned short*)d_ws;                    // 8192*512 bf16
    unsigned short* wt  = xb + (size_t)M_ * D_;                     // 4*512*512 bf16
    unsigned short* Q   = wt + 4 * D_ * D_;
    unsigned short* K   = Q + (size_t)M_ * D_;
    unsigned short* Vt  = K + (size_t)M_ * D_;                      // [B][512][2048]
    unsigned short* ctx = xb;                                       // alias: xb dead
    float* tmp = (float*)Q;                                         // alias: Q/K/Vt dead

    convert_x<<<dim3(M_ * D_ / 4 / 256), 256, 0, stream>>>(x, xb);
    transpose_w<<<dim3(8, 8, 4), 256, 0, stream>>>(wq, wk, wv, wo, wt);
    gemm_qkv<<<dim3(64, 4, 2), 256, 0, stream>>>(xb, wt, Q);
    gemm_vt<<<dim3(4, 16, 4), 256, 0, stream>>>(xb, wt + 2 * (size_t)D_ * D_, Vt);
    flash_attn<<<dim3(1024), 256, 0, stream>>>(Q, K, Vt, ctx);
    gemm_proj<<<dim3(64, 4), 256, 0, stream>>>(ctx, wt + 3 * (size_t)D_ * D_, tmp);
    ln_out<<<dim3(8192), 256, 0, stream>>>(tmp, x, bo, gamma, beta, out);
}

// Round 7
// 188.440 us; speedup vs baseline: 1.9128x; 1.0602x over previous
//
#include <hip/hip_runtime.h>
#include <hip/hip_bf16.h>

typedef __attribute__((ext_vector_type(8))) short short8;
typedef __attribute__((ext_vector_type(4))) float f32x4;

constexpr int B_ = 4, S_ = 2048, D_ = 512, H_ = 8, DP_ = 64;
constexpr int M_ = B_ * S_;  // 8192 rows

__device__ __forceinline__ unsigned short f2b(float f) {
    __hip_bfloat16 h = __float2bfloat16(f);
    return *reinterpret_cast<unsigned short*>(&h);
}

__device__ __forceinline__ void gload_lds16(const unsigned short* g, unsigned short* l) {
    __builtin_amdgcn_global_load_lds((const __attribute__((address_space(1))) void*)g,
                                     (__attribute__((address_space(3))) void*)l, 16, 0, 0);
}

#define MFMA16(a, b, c) __builtin_amdgcn_mfma_f32_16x16x32_bf16((a), (b), (c), 0, 0, 0)
#define ASM_BAR() asm volatile("s_barrier" ::: "memory")

// ---------------- fp32 -> bf16 convert (x) ----------------
__global__ __launch_bounds__(256)
void convert_x(const float* __restrict__ in, unsigned short* __restrict__ out) {
    int i = blockIdx.x * 256 + threadIdx.x;   // one float4 per thread
    float4 v = ((const float4*)in)[i];
    ushort4 o;
    o.x = f2b(v.x); o.y = f2b(v.y); o.z = f2b(v.z); o.w = f2b(v.w);
    ((ushort4*)out)[i] = o;
}

// ---------------- weight transpose + convert: Wt[n][k] = bf16(W[k][n]) ----------------
__global__ __launch_bounds__(256)
void transpose_w(const float* __restrict__ w0, const float* __restrict__ w1,
                 const float* __restrict__ w2, const float* __restrict__ w3,
                 unsigned short* __restrict__ outw) {
    const float* in = (blockIdx.z == 0) ? w0 : (blockIdx.z == 1) ? w1
                     : (blockIdx.z == 2) ? w2 : w3;
    unsigned short* out = outw + (size_t)blockIdx.z * D_ * D_;
    __shared__ float t[64][65];
    int k0 = blockIdx.x * 64, n0 = blockIdx.y * 64;
    int tx = threadIdx.x & 63, ty = threadIdx.x >> 6;
#pragma unroll
    for (int i = 0; i < 16; i++) {
        int r = ty * 16 + i;
        t[r][tx] = in[(size_t)(k0 + r) * D_ + n0 + tx];
    }
    __syncthreads();
#pragma unroll
    for (int i = 0; i < 16; i++) {
        int r = ty * 16 + i;
        out[(size_t)(n0 + r) * D_ + k0 + tx] = f2b(t[tx][r]);
    }
}

// ======== 128x128 / BK=64 GEMM body shared by the 3 projection kernels ========
// global_load_lds staging (R6-flash pattern): linear LDS dest, inverse-swizzled
// global source (chunk ^= row&7), XOR-swizzled b128 fragment reads (8 acc/bank
// = b128 minimum, verified in flash R6). Single-buffered 32KB LDS, 2-phase.

// ---------------- QKV GEMM (Q,K): [8192x512] @ W -> scatter to [B][H][S][64] ----------------
__global__ __launch_bounds__(256, 3)
void gemm_qkv(const unsigned short* __restrict__ X,
              const unsigned short* __restrict__ Wt,   // [2][512][512] transposed bf16
              unsigned short* __restrict__ QKV) {      // [2][B][H][S][64]
    const unsigned short* Bt = Wt + (size_t)blockIdx.z * D_ * D_;
    unsigned short* out = QKV + (size_t)blockIdx.z * M_ * D_;
    int m0 = blockIdx.x * 128, n0 = blockIdx.y * 128;
    int tid = threadIdx.x;
    int wave = tid >> 6, lane = tid & 63, l16 = lane & 15, quad = lane >> 4;
    int wm = (wave >> 1) * 64, wn = (wave & 1) * 64;

    __shared__ __align__(16) unsigned short As[128][64];
    __shared__ __align__(16) unsigned short Bs[128][64];

    const int psw = l16 & 7;
    const int drow = lane >> 3;          // 0..7, row within 8-row DMA group
    const int dsw = (lane & 7) ^ drow;   // inverse-swizzled source chunk

    f32x4 acc[4][4];
    const f32x4 zf = {0.f, 0.f, 0.f, 0.f};
#pragma unroll
    for (int i = 0; i < 4; i++)
#pragma unroll
        for (int j = 0; j < 4; j++) acc[i][j] = zf;

    for (int k0 = 0; k0 < D_; k0 += 64) {
        __syncthreads();   // waves done reading previous tile (drains lgkmcnt)
#pragma unroll
        for (int j = 0; j < 4; j++) {
            int r8 = wave * 32 + j * 8;
            gload_lds16(X  + (size_t)(m0 + r8 + drow) * D_ + k0 + dsw * 8, &As[r8][0]);
            gload_lds16(Bt + (size_t)(n0 + r8 + drow) * D_ + k0 + dsw * 8, &Bs[r8][0]);
        }
        __syncthreads();   // drains vmcnt(0): DMA complete for all waves
#pragma unroll
        for (int h = 0; h < 2; h++) {
            short8 af[4], bf[4];
#pragma unroll
            for (int mt = 0; mt < 4; mt++)
                af[mt] = *(const short8*)&As[wm + mt * 16 + l16][((h * 4 + quad) ^ psw) * 8];
#pragma unroll
            for (int nt = 0; nt < 4; nt++)
                bf[nt] = *(const short8*)&Bs[wn + nt * 16 + l16][((h * 4 + quad) ^ psw) * 8];
#pragma unroll
            for (int mt = 0; mt < 4; mt++)
#pragma unroll
                for (int nt = 0; nt < 4; nt++)
                    acc[mt][nt] = MFMA16(af[mt], bf[nt], acc[mt][nt]);
        }
    }
    // epilogue: C/D layout col=lane&15, row=quad*4+r; scatter to [B][H][S][64]
#pragma unroll
    for (int mt = 0; mt < 4; mt++)
#pragma unroll
        for (int nt = 0; nt < 4; nt++)
#pragma unroll
            for (int r = 0; r < 4; r++) {
                int m = m0 + wm + mt * 16 + quad * 4 + r;
                int n = n0 + wn + nt * 16 + l16;
                int bb = m >> 11, ss = m & 2047, hh = n >> 6, dd = n & 63;
                out[(((size_t)bb * H_ + hh) * S_ + ss) * DP_ + dd] = f2b(acc[mt][nt][r]);
            }
}

// ---------------- V^T GEMM: Vt_b = Wv^T (.) X_b^T  -> [B][512][2048] ----------------
__global__ __launch_bounds__(256, 3)
void gemm_vt(const unsigned short* __restrict__ X,
             const unsigned short* __restrict__ Wt,   // Wv^T [512][512] bf16
             unsigned short* __restrict__ Vt) {       // [B][D][S] bf16
    int bb = blockIdx.z;
    int m0 = blockIdx.x * 128, n0 = blockIdx.y * 128;
    int tid = threadIdx.x;
    int wave = tid >> 6, lane = tid & 63, l16 = lane & 15, quad = lane >> 4;
    int wm = (wave >> 1) * 64, wn = (wave & 1) * 64;

    __shared__ __align__(16) unsigned short As[128][64];
    __shared__ __align__(16) unsigned short Bs[128][64];

    const int psw = l16 & 7;
    const int drow = lane >> 3;
    const int dsw = (lane & 7) ^ drow;

    f32x4 acc[4][4];
    const f32x4 zf = {0.f, 0.f, 0.f, 0.f};
#pragma unroll
    for (int i = 0; i < 4; i++)
#pragma unroll
        for (int j = 0; j < 4; j++) acc[i][j] = zf;

    for (int k0 = 0; k0 < D_; k0 += 64) {
        __syncthreads();
#pragma unroll
        for (int j = 0; j < 4; j++) {
            int r8 = wave * 32 + j * 8;
            gload_lds16(Wt + (size_t)(m0 + r8 + drow) * D_ + k0 + dsw * 8,            &As[r8][0]);
            gload_lds16(X  + (size_t)(bb * S_ + n0 + r8 + drow) * D_ + k0 + dsw * 8,  &Bs[r8][0]);
        }
        __syncthreads();
#pragma unroll
        for (int h = 0; h < 2; h++) {
            short8 af[4], bf[4];
#pragma unroll
            for (int mt = 0; mt < 4; mt++)
                af[mt] = *(const short8*)&As[wm + mt * 16 + l16][((h * 4 + quad) ^ psw) * 8];
#pragma unroll
            for (int nt = 0; nt < 4; nt++)
                bf[nt] = *(const short8*)&Bs[wn + nt * 16 + l16][((h * 4 + quad) ^ psw) * 8];
#pragma unroll
            for (int mt = 0; mt < 4; mt++)
#pragma unroll
                for (int nt = 0; nt < 4; nt++)
                    acc[mt][nt] = MFMA16(af[mt], bf[nt], acc[mt][nt]);
        }
    }
#pragma unroll
    for (int mt = 0; mt < 4; mt++)
#pragma unroll
        for (int nt = 0; nt < 4; nt++)
#pragma unroll
            for (int r = 0; r < 4; r++) {
                int m = m0 + wm + mt * 16 + quad * 4 + r;   // d-row in [0,512)
                int n = n0 + wn + nt * 16 + l16;            // s in [0,2048)
                Vt[((size_t)bb * D_ + m) * S_ + n] = f2b(acc[mt][nt][r]);
            }
}

// ---------------- flash attention: K AND V DMA-staged, double-buffered, counted vmcnt ----
// (unchanged from R6: 70.4 us, MfmaUtil 19.4)
__global__ __launch_bounds__(256, 4)
void flash_attn(const unsigned short* __restrict__ Qg, const unsigned short* __restrict__ Kg,
                const unsigned short* __restrict__ Vt, unsigned short* __restrict__ ctx) {
    int bid0 = blockIdx.x;
    int bid = (bid0 & 7) * 128 + (bid0 >> 3);   // XCD swizzle: 4 heads per XCD (1024 = 8*128)
    int qt = bid & 31, hh = (bid >> 5) & 7, bb = bid >> 8;
    int tid = threadIdx.x;
    int wave = tid >> 6, lane = tid & 63, l16 = lane & 15, quad = lane >> 4;
    int qh = quad >> 1, ql = quad & 1;

    size_t bh = ((size_t)bb * H_ + hh) * S_ * DP_;
    const unsigned short* Qb = Qg + bh;
    const unsigned short* Kb = Kg + bh;
    const unsigned short* Vb = Vt + bh;   // V^T head slice: 64 rows (d), 2048 cols (s)

    __shared__ __align__(16) unsigned short Kls[2][64][64];  // [buf][key s][d]
    __shared__ __align__(16) unsigned short Vls[2][64][64];  // [buf][d][key s]
    __shared__ __align__(16) unsigned short Ps[4][16][64];   // per-wave P

    const int psw = l16 & 7;
    const int drow = (lane >> 3) & 7;
    const int dsw = (lane & 7) ^ drow;

    short8 qf0, qf1;
    {
        const unsigned short* qp = Qb + (size_t)(qt * 64 + wave * 16 + l16) * DP_ + quad * 8;
        qf0 = *(const short8*)qp;
        qf1 = *(const short8*)(qp + 32);
    }

    auto stage = [&](int kv, int b) {
#pragma unroll
        for (int j = 0; j < 2; j++) {
            int r8 = (wave * 2 + j) * 8;
            int r = r8 + drow;
            gload_lds16(Kb + (size_t)(kv + r) * DP_ + dsw * 8, &Kls[b][r8][0]);
            gload_lds16(Vb + (size_t)r * S_ + kv + dsw * 8,    &Vls[b][r8][0]);
        }
    };

    stage(0, 0);
    stage(64, 1);
    asm volatile("s_waitcnt vmcnt(4)" ::: "memory");
    ASM_BAR();

    const f32x4 zf = {0.f, 0.f, 0.f, 0.f};
    f32x4 oacc[4];
#pragma unroll
    for (int i = 0; i < 4; i++) oacc[i] = zf;
    float m2 = -1e30f;
    float lrow = 0.f;
    constexpr float c1 = 0.125f * 1.44269504088896f;  // (1/sqrt(64)) * log2(e)

    int cur = 0;
    for (int t = 0; t < 32; t++) {
        __builtin_amdgcn_s_setprio(1);
        f32x4 sacc[4];
#pragma unroll
        for (int nt = 0; nt < 4; nt++) {
            const unsigned short* kr = &Kls[cur][nt * 16 + l16][0];
            short8 kf0 = *(const short8*)(kr + ((quad ^ psw) * 8));
            short8 kf1 = *(const short8*)(kr + (((quad ^ 4) ^ psw) * 8));
            f32x4 s = zf;
            s = MFMA16(kf0, qf0, s);
            s = MFMA16(kf1, qf1, s);
            sacc[nt] = s;
        }
        __builtin_amdgcn_s_setprio(0);

        float t4[4];
#pragma unroll
        for (int nt = 0; nt < 4; nt++)
            t4[nt] = fmaxf(fmaxf(sacc[nt][0], sacc[nt][1]), fmaxf(sacc[nt][2], sacc[nt][3]));
        float g = fmaxf(fmaxf(t4[0], t4[1]), fmaxf(t4[2], t4[3]));
        g = fmaxf(g, __shfl_xor(g, 16));
        g = fmaxf(g, __shfl_xor(g, 32));
        g *= c1;
        float alpha = 1.0f;
        bool need = !__all(g <= m2 + 8.0f);
        if (need) {
            float m2n = fmaxf(m2, g);
            alpha = __builtin_amdgcn_exp2f(m2 - m2n);
            m2 = m2n;
        }
        float rs = 0.f;
#pragma unroll
        for (int nt = 0; nt < 4; nt++) {
            float p0 = __builtin_amdgcn_exp2f(__builtin_fmaf(sacc[nt][0], c1, -m2));
            float p1 = __builtin_amdgcn_exp2f(__builtin_fmaf(sacc[nt][1], c1, -m2));
            float p2 = __builtin_amdgcn_exp2f(__builtin_fmaf(sacc[nt][2], c1, -m2));
            float p3 = __builtin_amdgcn_exp2f(__builtin_fmaf(sacc[nt][3], c1, -m2));
            rs += (p0 + p1) + (p2 + p3);
            ushort4 pk;
            pk.x = f2b(p0); pk.y = f2b(p1); pk.z = f2b(p2); pk.w = f2b(p3);
            int c8 = (2 * nt + qh) ^ psw;
            *(ushort4*)&Ps[wave][l16][c8 * 8 + 4 * ql] = pk;
        }
        rs += __shfl_xor(rs, 16);
        rs += __shfl_xor(rs, 32);
        lrow = alpha * lrow + rs;
        if (need) {
            float al0 = __shfl(alpha, quad * 4 + 0);
            float al1 = __shfl(alpha, quad * 4 + 1);
            float al2 = __shfl(alpha, quad * 4 + 2);
            float al3 = __shfl(alpha, quad * 4 + 3);
#pragma unroll
            for (int ot = 0; ot < 4; ot++) {
                oacc[ot][0] *= al0; oacc[ot][1] *= al1;
                oacc[ot][2] *= al2; oacc[ot][3] *= al3;
            }
        }

        __builtin_amdgcn_s_setprio(1);
#pragma unroll
        for (int kt = 0; kt < 2; kt++) {
            int pc = ((kt * 4 + quad) ^ psw) * 8;
            short8 pf = *(const short8*)&Ps[wave][l16][pc];
#pragma unroll
            for (int ot = 0; ot < 4; ot++) {
                short8 vf = *(const short8*)&Vls[cur][ot * 16 + l16][pc];
                oacc[ot] = MFMA16(pf, vf, oacc[ot]);
            }
        }
        __builtin_amdgcn_s_setprio(0);

        ASM_BAR();
        if (t < 30) {
            stage((t + 2) * 64, cur);
            asm volatile("s_waitcnt vmcnt(4)" ::: "memory");
        } else {
            asm volatile("s_waitcnt vmcnt(0)" ::: "memory");
        }
        ASM_BAR();
        cur ^= 1;
    }

    float lb0 = __shfl(lrow, quad * 4 + 0);
    float lb1 = __shfl(lrow, quad * 4 + 1);
    float lb2 = __shfl(lrow, quad * 4 + 2);
    float lb3 = __shfl(lrow, quad * 4 + 3);
    float iv0 = __builtin_amdgcn_rcpf(lb0);
    float iv1 = __builtin_amdgcn_rcpf(lb1);
    float iv2 = __builtin_amdgcn_rcpf(lb2);
    float iv3 = __builtin_amdgcn_rcpf(lb3);
#pragma unroll
    for (int ot = 0; ot < 4; ot++) {
        int srow0 = qt * 64 + wave * 16 + quad * 4;
        size_t base = ((size_t)bb * S_ + srow0) * D_ + hh * DP_ + ot * 16 + l16;
        ctx[base]          = f2b(oacc[ot][0] * iv0);
        ctx[base + D_]     = f2b(oacc[ot][1] * iv1);
        ctx[base + 2 * D_] = f2b(oacc[ot][2] * iv2);
        ctx[base + 3 * D_] = f2b(oacc[ot][3] * iv3);
    }
}

// ---------------- output projection GEMM -> fp32 scratch ----------------
__global__ __launch_bounds__(256, 3)
void gemm_proj(const unsigned short* __restrict__ A,   // ctx [8192][512] bf16
               const unsigned short* __restrict__ Bt,  // Wo^T [512][512] bf16
               float* __restrict__ outf) {             // [8192][512] fp32
    int m0 = blockIdx.x * 128, n0 = blockIdx.y * 128;
    int tid = threadIdx.x;
    int wave = tid >> 6, lane = tid & 63, l16 = lane & 15, quad = lane >> 4;
    int wm = (wave >> 1) * 64, wn = (wave & 1) * 64;

    __shared__ __align__(16) unsigned short As[128][64];
    __shared__ __align__(16) unsigned short Bs[128][64];

    const int psw = l16 & 7;
    const int drow = lane >> 3;
    const int dsw = (lane & 7) ^ drow;

    f32x4 acc[4][4];
    const f32x4 zf = {0.f, 0.f, 0.f, 0.f};
#pragma unroll
    for (int i = 0; i < 4; i++)
#pragma unroll
        for (int j = 0; j < 4; j++) acc[i][j] = zf;

    for (int k0 = 0; k0 < D_; k0 += 64) {
        __syncthreads();
#pragma unroll
        for (int j = 0; j < 4; j++) {
            int r8 = wave * 32 + j * 8;
            gload_lds16(A  + (size_t)(m0 + r8 + drow) * D_ + k0 + dsw * 8, &As[r8][0]);
            gload_lds16(Bt + (size_t)(n0 + r8 + drow) * D_ + k0 + dsw * 8, &Bs[r8][0]);
        }
        __syncthreads();
#pragma unroll
        for (int h = 0; h < 2; h++) {
            short8 af[4], bf[4];
#pragma unroll
            for (int mt = 0; mt < 4; mt++)
                af[mt] = *(const short8*)&As[wm + mt * 16 + l16][((h * 4 + quad) ^ psw) * 8];
#pragma unroll
            for (int nt = 0; nt < 4; nt++)
                bf[nt] = *(const short8*)&Bs[wn + nt * 16 + l16][((h * 4 + quad) ^ psw) * 8];
#pragma unroll
            for (int mt = 0; mt < 4; mt++)
#pragma unroll
                for (int nt = 0; nt < 4; nt++)
                    acc[mt][nt] = MFMA16(af[mt], bf[nt], acc[mt][nt]);
        }
    }
#pragma unroll
    for (int mt = 0; mt < 4; mt++)
#pragma unroll
        for (int nt = 0; nt < 4; nt++)
#pragma unroll
            for (int r = 0; r < 4; r++) {
                int m = m0 + wm + mt * 16 + quad * 4 + r;
                int n = n0 + wn + nt * 16 + l16;
                outf[(size_t)m * D_ + n] = acc[mt][nt][r];
            }
}

// ---------------- bias + residual + LayerNorm: one row per wave, pure-shfl ----------------
__global__ __launch_bounds__(256, 8)
void ln_out(const float* __restrict__ tmp, const float* __restrict__ Xg,
            const float* __restrict__ bo, const float* __restrict__ gamma,
            const float* __restrict__ beta, float* __restrict__ outp) {
    int wave = threadIdx.x >> 6, lane = threadIdx.x & 63;
    int row = blockIdx.x * 4 + wave;
    const float4* t4 = (const float4*)(tmp + (size_t)row * D_);
    const float4* x4 = (const float4*)(Xg + (size_t)row * D_);
    const float4* b4 = (const float4*)bo;
    const float4* g4 = (const float4*)gamma;
    const float4* e4 = (const float4*)beta;
    float4* o4 = (float4*)(outp + (size_t)row * D_);

    float4 r[2];
    float sum = 0.f, sq = 0.f;
#pragma unroll
    for (int i = 0; i < 2; i++) {
        int c = lane + i * 64;
        float4 a = t4[c], x = x4[c], b = b4[c];
        r[i].x = a.x + x.x + b.x;
        r[i].y = a.y + x.y + b.y;
        r[i].z = a.z + x.z + b.z;
        r[i].w = a.w + x.w + b.w;
        sum += (r[i].x + r[i].y) + (r[i].z + r[i].w);
        sq += (r[i].x * r[i].x + r[i].y * r[i].y) + (r[i].z * r[i].z + r[i].w * r[i].w);
    }
#pragma unroll
    for (int off = 1; off < 64; off <<= 1) {
        sum += __shfl_xor(sum, off);
        sq += __shfl_xor(sq, off);
    }
    float mu = sum * (1.0f / D_);
    float var = sq * (1.0f / D_) - mu * mu;
    float rstd = rsqrtf(var + 1e-6f);
#pragma unroll
    for (int i = 0; i < 2; i++) {
        int c = lane + i * 64;
        float4 g = g4[c], e = e4[c];
        float4 o;
        o.x = (r[i].x - mu) * rstd * g.x + e.x;
        o.y = (r[i].y - mu) * rstd * g.y + e.y;
        o.z = (r[i].z - mu) * rstd * g.z + e.z;
        o.w = (r[i].w - mu) * rstd * g.w + e.w;
        o4[c] = o;
    }
}

extern "C" void kernel_launch(void* const* d_in, const int* in_sizes, int n_in,
                              void* d_out, int out_size, void* d_ws, size_t ws_size,
                              hipStream_t stream) {
    const float* x     = (const float*)d_in[0];
    const float* wq    = (const float*)d_in[1];
    const float* wk    = (const float*)d_in[2];
    const float* wv    = (const float*)d_in[3];
    const float* wo    = (const float*)d_in[4];
    const float* bo    = (const float*)d_in[5];
    const float* gamma = (const float*)d_in[6];
    const float* beta  = (const float*)d_in[7];
    float* out = (float*)d_out;

    // ws layout (bf16 elems unless noted), total 34 MB:
    //   [xb 8MB | wt 2MB | Q,K,Vt 24MB]
    //   ctx aliases xb (xb dead after the projection GEMMs). fp32 tmp aliases Q (dead after flash).
    unsigned short* xb  = (unsigned short*)d_ws;                    // 8192*512 bf16
    unsigned short* wt  = xb + (size_t)M_ * D_;                     // 4*512*512 bf16
    unsigned short* Q   = wt + 4 * D_ * D_;
    unsigned short* K   = Q + (size_t)M_ * D_;
    unsigned short* Vt  = K + (size_t)M_ * D_;                      // [B][512][2048]
    unsigned short* ctx = xb;                                       // alias: xb dead
    float* tmp = (float*)Q;                                         // alias: Q/K/Vt dead

    convert_x<<<dim3(M_ * D_ / 4 / 256), 256, 0, stream>>>(x, xb);
    transpose_w<<<dim3(8, 8, 4), 256, 0, stream>>>(wq, wk, wv, wo, wt);
    gemm_qkv<<<dim3(64, 4, 2), 256, 0, stream>>>(xb, wt, Q);
    gemm_vt<<<dim3(4, 16, 4), 256, 0, stream>>>(xb, wt + 2 * (size_t)D_ * D_, Vt);
    flash_attn<<<dim3(1024), 256, 0, stream>>>(Q, K, Vt, ctx);
    gemm_proj<<<dim3(64, 4), 256, 0, stream>>>(ctx, wt + 3 * (size_t)D_ * D_, tmp);
    ln_out<<<dim3(2048), 256, 0, stream>>>(tmp, x, bo, gamma, beta, out);
}